// Round 20
// baseline (552.106 us; speedup 1.0000x reference)
//
#include <hip/hip_runtime.h>
#include <hip/hip_bf16.h>
#include <cstdint>
#include <cstddef>

#define DEPTH 4
#define DIM 512
#define DFF 2048
#define VOCAB 4096
#define NB 2
#define LSEQ 4096
#define MR (NB*LSEQ)      // 8192 rows
#define EPSL 1e-5f
#define NC 256            // scan chunks per sequence
#define TCH 16            // chunk length (NC*TCH == LSEQ)

typedef __attribute__((ext_vector_type(8))) short  s8v;
typedef __attribute__((ext_vector_type(4))) float  f4v;
typedef __attribute__((ext_vector_type(8))) __bf16 bf8v;

__device__ __forceinline__ unsigned short f2b(float f) {
  union { float f; unsigned int u; } v; v.f = f;
  unsigned int r = v.u + 0x7FFFu + ((v.u >> 16) & 1u);   // RNE
  return (unsigned short)(r >> 16);
}
__device__ __forceinline__ float b2f(unsigned short u) {
  union { unsigned int u; float f; } v; v.u = ((unsigned int)u) << 16; return v.f;
}

// global->LDS direct load, 16B per lane (LDS dest: wave-uniform base + lane*16).
__device__ __forceinline__ void gld16(const void* g, void* l) {
  __builtin_amdgcn_global_load_lds(
      (const __attribute__((address_space(1))) unsigned int*)(uintptr_t)g,
      (__attribute__((address_space(3))) unsigned int*)(uintptr_t)l,
      16, 0, 0);
}

// counted vmem wait (T4: never drain to 0 in steady state)
template<int N> __device__ __forceinline__ void wvm() {
  if constexpr (N == 12)     asm volatile("s_waitcnt vmcnt(12)" ::: "memory");
  else if constexpr (N == 8) asm volatile("s_waitcnt vmcnt(8)" ::: "memory");
  else if constexpr (N == 6) asm volatile("s_waitcnt vmcnt(6)" ::: "memory");
  else if constexpr (N == 4) asm volatile("s_waitcnt vmcnt(4)" ::: "memory");
  else if constexpr (N == 3) asm volatile("s_waitcnt vmcnt(3)" ::: "memory");
  else                       asm volatile("s_waitcnt vmcnt(0)" ::: "memory");
}

__device__ __forceinline__ void wred64(float& s, float& s2) {
#pragma unroll
  for (int off = 32; off; off >>= 1) { s += __shfl_xor(s, off, 64); s2 += __shfl_xor(s2, off, 64); }
}

// ---------------- merged f32 -> bf16 convert (one dispatch) [R11-proven] ----------------
#define NX8 4194304   // x:    8192*4096/8
#define NW8  262144   // Win:  512*4096/8
#define N18  524288   // W1:   4*2048*512/8
#define N28  524288   // W2:   4*512*2048/8
#define NO8  262144   // Wout: 4096*512/8
__global__ void __launch_bounds__(256) cvt_all(
    const float* __restrict__ x,  const float* __restrict__ Win,
    const float* __restrict__ W1, const float* __restrict__ W2,
    const float* __restrict__ Wout,
    unsigned short* __restrict__ xb,  unsigned short* __restrict__ Winb,
    unsigned short* __restrict__ W1b, unsigned short* __restrict__ W2b,
    unsigned short* __restrict__ Woutb)
{
  long i = (long)blockIdx.x * 256 + threadIdx.x;   // segment index (8 elems)
  const float* src; unsigned short* dst; long j;
  if (i < NX8)                         { src = x;    dst = xb;    j = i; }
  else if (i < NX8 + NW8)              { src = Win;  dst = Winb;  j = i - NX8; }
  else if (i < NX8 + NW8 + N18)        { src = W1;   dst = W1b;   j = i - NX8 - NW8; }
  else if (i < NX8 + NW8 + N18 + N28)  { src = W2;   dst = W2b;   j = i - NX8 - NW8 - N18; }
  else                                 { src = Wout; dst = Woutb; j = i - NX8 - NW8 - N18 - N28; }
  const f4v* p = (const f4v*)(src + j * 8);
  f4v a = p[0], b = p[1];
  s8v o;
  o[0]=(short)f2b(a[0]); o[1]=(short)f2b(a[1]); o[2]=(short)f2b(a[2]); o[3]=(short)f2b(a[3]);
  o[4]=(short)f2b(b[0]); o[5]=(short)f2b(b[1]); o[6]=(short)f2b(b[2]); o[7]=(short)f2b(b[3]);
  *(s8v*)(dst + j * 8) = o;
}

// ---------------- sconv helpers ----------------
__device__ __forceinline__ void phz2p(float re, float im, float& pre, float& pim) {
  float r = sqrtf(re * re + im * im);
  float t = (r > 1e-20f) ? (tanhf(r) / r) : 1.0f;
  pre = t * re; pim = t * im;
}

// LN1+SiLU of the ls tile -> y (bf16 global) AND ls (bf16-rounded f32, so the
// local scan uses EXACTLY the values scan_c_ln2 will replay from y). [R15-proven]
__device__ __forceinline__ void ln_silu_emit(
    float (*ls)[DIM], unsigned short* __restrict__ y,
    const float* __restrict__ lnw, const float* __restrict__ lnb,
    int wave, int c8, int b, int c)
{
  f4v w0 = *(const f4v*)(lnw + c8), w1 = *(const f4v*)(lnw + c8 + 4);
  f4v b0 = *(const f4v*)(lnb + c8), b1 = *(const f4v*)(lnb + c8 + 4);
#pragma unroll
  for (int jj = 0; jj < 2; ++jj) {
    int j = wave * 2 + jj;
    f4v v0 = *(const f4v*)&ls[j][c8];
    f4v v1 = *(const f4v*)&ls[j][c8 + 4];
    float s = 0.f, s2 = 0.f;
#pragma unroll
    for (int q = 0; q < 4; ++q) { s += v0[q]; s2 += v0[q]*v0[q]; s += v1[q]; s2 += v1[q]*v1[q]; }
    wred64(s, s2);
    float mu = s * (1.f / DIM);
    float rs = rsqrtf(s2 * (1.f / DIM) - mu * mu + EPSL);
    s8v ob;
    f4v o0, o1;
#pragma unroll
    for (int q = 0; q < 4; ++q) {
      float a = (v0[q] - mu) * rs * w0[q] + b0[q];
      a = a / (1.f + __expf(-a));
      unsigned short ua = f2b(a);
      ob[q] = (short)ua; o0[q] = b2f(ua);
      float e = (v1[q] - mu) * rs * w1[q] + b1[q];
      e = e / (1.f + __expf(-e));
      unsigned short ue = f2b(e);
      ob[4 + q] = (short)ue; o1[q] = b2f(ue);
    }
    *(s8v*)(y + ((size_t)b * LSEQ + (size_t)c * TCH + j) * DIM + c8) = ob;
    *(f4v*)&ls[j][c8]     = o0;
    *(f4v*)&ls[j][c8 + 4] = o1;
  }
}

// ---------------- fused: LN1+SiLU -> y(bf16) ; chunk-local scan -> stA (h bf16 read-only)
__global__ void __launch_bounds__(512) ln_scan(
    const unsigned short* __restrict__ h,
    const float* __restrict__ lnw, const float* __restrict__ lnb,
    const float* __restrict__ pr, const float* __restrict__ pi,
    unsigned short* __restrict__ y, float* __restrict__ stA)
{
  __shared__ float ls[TCH][DIM];
  const int d = threadIdx.x;
  const int c = blockIdx.x, b = blockIdx.y;
  const size_t rbase = ((size_t)b * LSEQ + (size_t)c * TCH) * DIM + d;
#pragma unroll 4
  for (int j = 0; j < TCH; ++j) ls[j][d] = b2f(h[rbase + (size_t)j * DIM]);
  __syncthreads();
  const int wave = threadIdx.x >> 6, lane = threadIdx.x & 63;
  ln_silu_emit(ls, y, lnw, lnb, wave, lane * 8, b, c);
  __syncthreads();
  float pre, pim; phz2p(pr[d], pi[d], pre, pim);
  float sre = 0.f, sim = 0.f;
#pragma unroll
  for (int j = 0; j < TCH; ++j) {
    float xv = ls[j][d];
    float nre = fmaf(pre, sre, fmaf(-pim, sim, xv));
    float nim = fmaf(pre, sim, pim * sre);
    sre = nre; sim = nim;
  }
  size_t o = (((size_t)b * NC + c) * DIM + d) * 2;
  stA[o] = sre; stA[o + 1] = sim;
}

// ---------------- scan_b: sequential carry over chunks (batch-8 load prefetch) [R7]
__global__ void __launch_bounds__(256) scan_b(
    const float* __restrict__ stA, float* __restrict__ carry,
    const float* __restrict__ pr, const float* __restrict__ pi,
    const float* __restrict__ lcr, const float* __restrict__ lci)
{
  int idx = blockIdx.x * 256 + threadIdx.x;   // 0..NB*DIM-1
  int b = idx >> 9, d = idx & (DIM - 1);
  float pre, pim; phz2p(pr[d], pi[d], pre, pim);
  float qre = pre, qim = pim;                  // p^TCH, TCH=16 -> 4 squarings
#pragma unroll
  for (int t = 0; t < 4; ++t) { float nr = qre*qre - qim*qim; float ni = 2.f*qre*qim; qre = nr; qim = ni; }
  float cre = lcr[d], cim = lci[d];
  const size_t base = (size_t)b * NC * DIM * 2 + (size_t)d * 2;
  for (int c0 = 0; c0 < NC; c0 += 8) {
    float ar[8], ai[8];
#pragma unroll
    for (int k = 0; k < 8; ++k) {
      size_t o = base + (size_t)(c0 + k) * DIM * 2;
      ar[k] = stA[o]; ai[k] = stA[o + 1];
    }
#pragma unroll
    for (int k = 0; k < 8; ++k) {
      size_t o = base + (size_t)(c0 + k) * DIM * 2;
      carry[o] = cre; carry[o + 1] = cim;
      float nr = fmaf(qre, cre, fmaf(-qim, cim, ar[k]));
      float ni = fmaf(qre, cim, fmaf(qim, cre, ai[k]));
      cre = nr; cim = ni;
    }
  }
}

// ---------------- fused: carry-replay (y bf16) + h(bf16) += Re(s)*scl ; LN2 -> yb (bf16)
__global__ void __launch_bounds__(512) scan_c_ln2(
    const unsigned short* __restrict__ y, unsigned short* __restrict__ h,
    const float* __restrict__ carry,
    const float* __restrict__ pr, const float* __restrict__ pi,
    const float* __restrict__ scl,
    const float* __restrict__ lnw, const float* __restrict__ lnb,
    unsigned short* __restrict__ yb)
{
  __shared__ float ls[TCH][DIM];
  const int d = threadIdx.x;
  const int c = blockIdx.x, b = blockIdx.y;
  float pre, pim; phz2p(pr[d], pi[d], pre, pim);
  size_t co = (((size_t)b * NC + c) * DIM + d) * 2;
  float sre = carry[co], sim = carry[co + 1];
  const float sc = scl[d];
  const size_t rbase = ((size_t)b * LSEQ + (size_t)c * TCH) * DIM + d;
#pragma unroll 4
  for (int j = 0; j < TCH; ++j) {
    size_t o = rbase + (size_t)j * DIM;
    float xv = b2f(y[o]);
    float nre = fmaf(pre, sre, fmaf(-pim, sim, xv));
    float nim = fmaf(pre, sim, pim * sre);
    sre = nre; sim = nim;
    float hv = b2f(h[o]) + sre * sc;
    unsigned short hq = f2b(hv);
    h[o] = hq;
    ls[j][d] = b2f(hq);
  }
  __syncthreads();
  const int wave = threadIdx.x >> 6, lane = threadIdx.x & 63;
  const int c8 = lane * 8;
  f4v w0 = *(const f4v*)(lnw + c8), w1 = *(const f4v*)(lnw + c8 + 4);
  f4v b0 = *(const f4v*)(lnb + c8), b1 = *(const f4v*)(lnb + c8 + 4);
#pragma unroll
  for (int jj = 0; jj < 2; ++jj) {
    int j = wave * 2 + jj;
    f4v v0 = *(const f4v*)&ls[j][c8];
    f4v v1 = *(const f4v*)&ls[j][c8 + 4];
    float s = 0.f, s2 = 0.f;
#pragma unroll
    for (int q = 0; q < 4; ++q) { s += v0[q]; s2 += v0[q]*v0[q]; s += v1[q]; s2 += v1[q]*v1[q]; }
    wred64(s, s2);
    float mu = s * (1.f / DIM);
    float rs = rsqrtf(s2 * (1.f / DIM) - mu * mu + EPSL);
    s8v o;
#pragma unroll
    for (int q = 0; q < 4; ++q) {
      o[q]     = (short)f2b((v0[q] - mu) * rs * w0[q] + b0[q]);
      o[4 + q] = (short)f2b((v1[q] - mu) * rs * w1[q] + b1[q]);
    }
    *(s8v*)(yb + ((size_t)b * LSEQ + (size_t)c * TCH + j) * DIM + c8) = o;
  }
}

// ---------------- fused: final LN -> yb (bf16); h bf16 read-only ----------------
__global__ void __launch_bounds__(512) ln_final(
    const unsigned short* __restrict__ h,
    const float* __restrict__ lnw, const float* __restrict__ lnb,
    unsigned short* __restrict__ yb)
{
  __shared__ float ls[TCH][DIM];
  const int d = threadIdx.x;
  const int c = blockIdx.x, b = blockIdx.y;
  const size_t rbase = ((size_t)b * LSEQ + (size_t)c * TCH) * DIM + d;
#pragma unroll 4
  for (int j = 0; j < TCH; ++j) ls[j][d] = b2f(h[rbase + (size_t)j * DIM]);
  __syncthreads();
  const int wave = threadIdx.x >> 6, lane = threadIdx.x & 63;
  const int c8 = lane * 8;
  f4v w0 = *(const f4v*)(lnw + c8), w1 = *(const f4v*)(lnw + c8 + 4);
  f4v b0 = *(const f4v*)(lnb + c8), b1 = *(const f4v*)(lnb + c8 + 4);
#pragma unroll
  for (int jj = 0; jj < 2; ++jj) {
    int j = wave * 2 + jj;
    f4v v0 = *(const f4v*)&ls[j][c8];
    f4v v1 = *(const f4v*)&ls[j][c8 + 4];
    float s = 0.f, s2 = 0.f;
#pragma unroll
    for (int q = 0; q < 4; ++q) { s += v0[q]; s2 += v0[q]*v0[q]; s += v1[q]; s2 += v1[q]*v1[q]; }
    wred64(s, s2);
    float mu = s * (1.f / DIM);
    float rs = rsqrtf(s2 * (1.f / DIM) - mu * mu + EPSL);
    s8v o;
#pragma unroll
    for (int q = 0; q < 4; ++q) {
      o[q]     = (short)f2b((v0[q] - mu) * rs * w0[q] + b0[q]);
      o[4 + q] = (short)f2b((v1[q] - mu) * rs * w1[q] + b1[q]);
    }
    *(s8v*)(yb + ((size_t)b * LSEQ + (size_t)c * TCH + j) * DIM + c8) = o;
  }
}

// ---------------- pipelined bf16 MFMA GEMM, A[M,K] x B[N,K]^T, 128xBN ----------------
// Depth-2 counted-vmcnt pipeline, 3 LDS buffer sets (R5-proven sync structure).
// BN in {64,128,256}; blocks/CU = 4/3/2. Template fully generic in BN.
// EPI 0: Cf = acc+bias ; EPI 1: Cb = bf16(silu(acc+bias)) ;
// EPI 2: Cb(bf16 h) RMW: h = bf16(b2f(h) + acc + bias) ;
// EPI 4: Cb = bf16(acc+bias)  (direct bf16 h write, token GEMM)
template<int EPI, int BN>
__global__ void __launch_bounds__(256, BN == 64 ? 4 : (BN == 256 ? 2 : 3)) gemm_p(
    const unsigned short* __restrict__ A, const unsigned short* __restrict__ Bm,
    const float* __restrict__ bias,
    float* __restrict__ Cf, unsigned short* __restrict__ Cb,
    int N, int Keff, int lda, int ldb)
{
  constexpr int WN  = BN / 2;        // per-wave N extent
  constexpr int NJ  = WN / 16;       // N fragments per wave
  constexpr int VPT = 2 + BN / 64;   // vmem instrs per tile per thread
  __shared__ unsigned short As[3][128 * 32];
  __shared__ unsigned short Bs[3][BN * 32];
  const int tid  = threadIdx.x;
  const int lane = tid & 63, wave = tid >> 6;
  const int wm = wave >> 1, wn = wave & 1;
  const int fr = lane & 15, fq = lane >> 4;

  // chunked bijective XCD swizzle (all grids have nwg_xy % 8 == 0)
  int bx, by;
  {
    int gx = gridDim.x;
    int nwg = gx * gridDim.y;
    int b = blockIdx.y * gx + blockIdx.x;
    int lid = (b & 7) * (nwg >> 3) + (b >> 3);
    bx = lid % gx; by = lid / gx;
  }
  const int m0 = by * 128, n0 = bx * BN;
  const int nkt = Keff >> 5;

  f4v acc[4][NJ];
#pragma unroll
  for (int i = 0; i < 4; ++i)
#pragma unroll
    for (int j = 0; j < NJ; ++j) acc[i][j] = (f4v){0.f, 0.f, 0.f, 0.f};

  const int row2 = tid >> 2, col2 = (tid & 3) << 3;
  auto stage = [&](int buf, int kt) {
    const unsigned short* Ab = A  + (size_t)m0 * lda + kt * 32;
    const unsigned short* Bb = Bm + (size_t)n0 * ldb + kt * 32;
    gld16(Ab + (size_t)row2 * lda + col2,        &As[buf][tid * 8]);
    gld16(Ab + (size_t)(row2 + 64) * lda + col2, &As[buf][(256 + tid) * 8]);
#pragma unroll
    for (int r = 0; r < BN / 64; ++r)
      gld16(Bb + (size_t)(row2 + 64 * r) * ldb + col2, &Bs[buf][(r * 256 + tid) * 8]);
  };

  stage(0, 0);
  stage(1, 1);

  int b0 = 0, b1 = 1, b2 = 2;
  for (int kt = 0; kt < nkt; ++kt) {
    bool pf = (kt + 2 < nkt);
    if (pf) stage(b2, kt + 2);
    if (pf)                    wvm<2 * VPT>();  // tiles kt+1,kt+2 in flight; kt retired
    else if (kt + 1 < nkt)     wvm<VPT>();
    else                       wvm<0>();
    __builtin_amdgcn_s_barrier();
    __builtin_amdgcn_sched_barrier(0);
    bf8v av[4], bv[NJ];
#pragma unroll
    for (int i = 0; i < 4; ++i)
      av[i] = *(const bf8v*)&As[b0][(wm * 64 + i * 16 + fr) * 32 + fq * 8];
#pragma unroll
    for (int j = 0; j < NJ; ++j)
      bv[j] = *(const bf8v*)&Bs[b0][(wn * WN + j * 16 + fr) * 32 + fq * 8];
#pragma unroll
    for (int i = 0; i < 4; ++i)
#pragma unroll
      for (int j = 0; j < NJ; ++j)
        acc[i][j] = __builtin_amdgcn_mfma_f32_16x16x32_bf16(av[i], bv[j], acc[i][j], 0, 0, 0);
    __builtin_amdgcn_sched_barrier(0);
    __builtin_amdgcn_s_barrier();
    int t = b0; b0 = b1; b1 = b2; b2 = t;
  }

  // epilogue: C[m0 + wm*64 + i*16 + fq*4 + r][n0 + wn*WN + j*16 + fr]
#pragma unroll
  for (int j = 0; j < NJ; ++j) {
    const int col = n0 + wn * WN + j * 16 + fr;
    const float bsv = bias[col];
#pragma unroll
    for (int i = 0; i < 4; ++i) {
#pragma unroll
      for (int r = 0; r < 4; ++r) {
        const int row = m0 + wm * 64 + i * 16 + fq * 4 + r;
        const size_t off = (size_t)row * N + col;
        float v = acc[i][j][r] + bsv;
        if constexpr (EPI == 0) {
          Cf[off] = v;
        } else if constexpr (EPI == 1) {
          float sv = v / (1.f + __expf(-v));
          Cb[off] = f2b(sv);
        } else if constexpr (EPI == 2) {
          Cb[off] = f2b(b2f(Cb[off]) + v);   // bf16 residual RMW
        } else {
          Cb[off] = f2b(v);                  // direct bf16 write (token h)
        }
      }
    }
  }
}

// ---------------- orchestration ----------------
extern "C" void kernel_launch(void* const* d_in, const int* in_sizes, int n_in,
                              void* d_out, int out_size, void* d_ws, size_t ws_size,
                              hipStream_t stream)
{
  (void)in_sizes; (void)n_in; (void)out_size; (void)ws_size;
  const float* x    = (const float*)d_in[0];
  const float* Win  = (const float*)d_in[1];
  const float* bin  = (const float*)d_in[2];
  const float* ln1w = (const float*)d_in[3];
  const float* ln1b = (const float*)d_in[4];
  const float* phzr = (const float*)d_in[5];
  const float* phzi = (const float*)d_in[6];
  const float* lcr  = (const float*)d_in[7];
  const float* lci  = (const float*)d_in[8];
  const float* scl  = (const float*)d_in[9];
  const float* ln2w = (const float*)d_in[10];
  const float* ln2b = (const float*)d_in[11];
  const float* W1   = (const float*)d_in[12];
  const float* b1   = (const float*)d_in[13];
  const float* W2   = (const float*)d_in[14];
  const float* b2   = (const float*)d_in[15];
  const float* lnlw = (const float*)d_in[16];
  const float* lnlb = (const float*)d_in[17];
  const float* Wout = (const float*)d_in[18];
  const float* bout = (const float*)d_in[19];

  char* wsp = (char*)d_ws;
  auto alloc = [&](size_t bytes) { char* p = wsp; wsp += (bytes + 255) & ~(size_t)255; return p; };
  unsigned short* h     = (unsigned short*)alloc((size_t)MR * DIM * 2);   // bf16 residual
  unsigned short* y     = (unsigned short*)alloc((size_t)MR * DIM * 2);   // bf16
  unsigned short* yb    = (unsigned short*)alloc((size_t)MR * DIM * 2);
  unsigned short* Winb  = (unsigned short*)alloc((size_t)DIM * VOCAB * 2);
  unsigned short* W1b   = (unsigned short*)alloc((size_t)DEPTH * DFF * DIM * 2);
  unsigned short* W2b   = (unsigned short*)alloc((size_t)DEPTH * DIM * DFF * 2);
  unsigned short* Woutb = (unsigned short*)alloc((size_t)VOCAB * DIM * 2);
  float*          stA   = (float*)alloc((size_t)NB * NC * DIM * 2 * 4);
  float*          carry = (float*)alloc((size_t)NB * NC * DIM * 2 * 4);

  // d_out (128 MiB) doubles as scratch:
  //   xb   (bf16, 64 MiB) at [0, 64Mi) — dies after token_in GEMM
  //   act1 (bf16, 32 MiB) at [0, 32Mi) — per-layer FFN activation (after xb dead)
  // Final GEMM overwrites d_out fully.
  unsigned short* xb   = (unsigned short*)d_out;
  unsigned short* act1 = (unsigned short*)d_out;

  dim3 blk(256);
  dim3 fblk(512);
  dim3 fgrid(NC, NB);
  // one merged convert dispatch: x + Win + W1 + W2 + Wout
  cvt_all<<<dim3((NX8 + NW8 + N18 + N28 + NO8) / 256), blk, 0, stream>>>(
      x, Win, W1, W2, Wout, xb, Winb, W1b, W2b, Woutb);

  // h = bf16(xb @ Win^T + bin) : BN=64, direct bf16 epilogue -> 8x64 = 512 blocks
  gemm_p<4, 64><<<dim3(DIM / 64, MR / 128, 1), blk, 0, stream>>>(
      xb, Winb, bin, nullptr, h, DIM, VOCAB, VOCAB, VOCAB);
  // y = silu(LN1_0(h)) (bf16) ; stA  (same kernel as later layers)
  ln_scan<<<fgrid, fblk, 0, stream>>>(h, ln1w, ln1b, phzr, phzi, y, stA);

  for (int l = 0; l < DEPTH; ++l) {
    scan_b<<<dim3((NB * DIM) / 256), blk, 0, stream>>>(stA, carry, phzr + l * DIM, phzi + l * DIM,
                                                       lcr + l * DIM, lci + l * DIM);
    scan_c_ln2<<<fgrid, fblk, 0, stream>>>(y, h, carry, phzr + l * DIM, phzi + l * DIM,
                                           scl + l * DIM, ln2w + l * DIM, ln2b + l * DIM, yb);
    // act1 = silu(yb @ W1^T + b1), bf16 (BN=256: grid 8x64 = 512 blocks)
    gemm_p<1, 256><<<dim3(DFF / 256, MR / 128, 1), blk, 0, stream>>>(
        yb, W1b + (size_t)l * DFF * DIM, b1 + l * DFF, nullptr, act1, DFF, DIM, DIM, DIM);
    // h += act1 @ W2^T + b2  (BN=64, bf16 residual RMW in epilogue)
    gemm_p<2, 64><<<dim3(DIM / 64, MR / 128, 1), blk, 0, stream>>>(
        act1, W2b + (size_t)l * DIM * DFF, b2 + l * DIM, nullptr, h, DIM, DFF, DFF, DFF);
    if (l < DEPTH - 1) {
      ln_scan<<<fgrid, fblk, 0, stream>>>(h, ln1w + (l + 1) * DIM, ln1b + (l + 1) * DIM,
                                          phzr + (l + 1) * DIM, phzi + (l + 1) * DIM, y, stA);
    }
  }
  // final: yb = LN_last(h)
  ln_final<<<fgrid, fblk, 0, stream>>>(h, lnlw, lnlb, yb);
  // out = yb @ Wout^T + bout (BN=256: grid 16x64 = 1024 blocks)
  gemm_p<0, 256><<<dim3(VOCAB / 256, MR / 128, 1), blk, 0, stream>>>(
      yb, Woutb, bout, (float*)d_out, nullptr, VOCAB, DIM, DIM, DIM);
}

// Round 21
// 542.987 us; speedup vs baseline: 1.0168x; 1.0168x over previous
//
#include <hip/hip_runtime.h>
#include <hip/hip_bf16.h>
#include <cstdint>
#include <cstddef>

#define DEPTH 4
#define DIM 512
#define DFF 2048
#define VOCAB 4096
#define NB 2
#define LSEQ 4096
#define MR (NB*LSEQ)      // 8192 rows
#define EPSL 1e-5f
#define NC 256            // scan chunks per sequence
#define TCH 16            // chunk length (NC*TCH == LSEQ)

typedef __attribute__((ext_vector_type(8))) short  s8v;
typedef __attribute__((ext_vector_type(4))) float  f4v;
typedef __attribute__((ext_vector_type(8))) __bf16 bf8v;

__device__ __forceinline__ unsigned short f2b(float f) {
  union { float f; unsigned int u; } v; v.f = f;
  unsigned int r = v.u + 0x7FFFu + ((v.u >> 16) & 1u);   // RNE
  return (unsigned short)(r >> 16);
}
__device__ __forceinline__ float b2f(unsigned short u) {
  union { unsigned int u; float f; } v; v.u = ((unsigned int)u) << 16; return v.f;
}

// global->LDS direct load, 16B per lane (LDS dest: wave-uniform base + lane*16).
__device__ __forceinline__ void gld16(const void* g, void* l) {
  __builtin_amdgcn_global_load_lds(
      (const __attribute__((address_space(1))) unsigned int*)(uintptr_t)g,
      (__attribute__((address_space(3))) unsigned int*)(uintptr_t)l,
      16, 0, 0);
}

// counted vmem wait (T4: never drain to 0 in steady state)
template<int N> __device__ __forceinline__ void wvm() {
  if constexpr (N == 12)     asm volatile("s_waitcnt vmcnt(12)" ::: "memory");
  else if constexpr (N == 8) asm volatile("s_waitcnt vmcnt(8)" ::: "memory");
  else if constexpr (N == 6) asm volatile("s_waitcnt vmcnt(6)" ::: "memory");
  else if constexpr (N == 4) asm volatile("s_waitcnt vmcnt(4)" ::: "memory");
  else if constexpr (N == 3) asm volatile("s_waitcnt vmcnt(3)" ::: "memory");
  else                       asm volatile("s_waitcnt vmcnt(0)" ::: "memory");
}

__device__ __forceinline__ void wred64(float& s, float& s2) {
#pragma unroll
  for (int off = 32; off; off >>= 1) { s += __shfl_xor(s, off, 64); s2 += __shfl_xor(s2, off, 64); }
}

// ---------------- merged f32 -> bf16 convert (one dispatch) [R11-proven] ----------------
#define NX8 4194304   // x:    8192*4096/8
#define NW8  262144   // Win:  512*4096/8
#define N18  524288   // W1:   4*2048*512/8
#define N28  524288   // W2:   4*512*2048/8
#define NO8  262144   // Wout: 4096*512/8
__global__ void __launch_bounds__(256) cvt_all(
    const float* __restrict__ x,  const float* __restrict__ Win,
    const float* __restrict__ W1, const float* __restrict__ W2,
    const float* __restrict__ Wout,
    unsigned short* __restrict__ xb,  unsigned short* __restrict__ Winb,
    unsigned short* __restrict__ W1b, unsigned short* __restrict__ W2b,
    unsigned short* __restrict__ Woutb)
{
  long i = (long)blockIdx.x * 256 + threadIdx.x;   // segment index (8 elems)
  const float* src; unsigned short* dst; long j;
  if (i < NX8)                         { src = x;    dst = xb;    j = i; }
  else if (i < NX8 + NW8)              { src = Win;  dst = Winb;  j = i - NX8; }
  else if (i < NX8 + NW8 + N18)        { src = W1;   dst = W1b;   j = i - NX8 - NW8; }
  else if (i < NX8 + NW8 + N18 + N28)  { src = W2;   dst = W2b;   j = i - NX8 - NW8 - N18; }
  else                                 { src = Wout; dst = Woutb; j = i - NX8 - NW8 - N18 - N28; }
  const f4v* p = (const f4v*)(src + j * 8);
  f4v a = p[0], b = p[1];
  s8v o;
  o[0]=(short)f2b(a[0]); o[1]=(short)f2b(a[1]); o[2]=(short)f2b(a[2]); o[3]=(short)f2b(a[3]);
  o[4]=(short)f2b(b[0]); o[5]=(short)f2b(b[1]); o[6]=(short)f2b(b[2]); o[7]=(short)f2b(b[3]);
  *(s8v*)(dst + j * 8) = o;
}

// ---------------- sconv helpers ----------------
__device__ __forceinline__ void phz2p(float re, float im, float& pre, float& pim) {
  float r = sqrtf(re * re + im * im);
  float t = (r > 1e-20f) ? (tanhf(r) / r) : 1.0f;
  pre = t * re; pim = t * im;
}

// LN1+SiLU of the ls tile -> y (bf16 global) AND ls (bf16-rounded f32, so the
// local scan uses EXACTLY the values scan_c_ln2 will replay from y). [R15-proven]
__device__ __forceinline__ void ln_silu_emit(
    float (*ls)[DIM], unsigned short* __restrict__ y,
    const float* __restrict__ lnw, const float* __restrict__ lnb,
    int wave, int c8, int b, int c)
{
  f4v w0 = *(const f4v*)(lnw + c8), w1 = *(const f4v*)(lnw + c8 + 4);
  f4v b0 = *(const f4v*)(lnb + c8), b1 = *(const f4v*)(lnb + c8 + 4);
#pragma unroll
  for (int jj = 0; jj < 2; ++jj) {
    int j = wave * 2 + jj;
    f4v v0 = *(const f4v*)&ls[j][c8];
    f4v v1 = *(const f4v*)&ls[j][c8 + 4];
    float s = 0.f, s2 = 0.f;
#pragma unroll
    for (int q = 0; q < 4; ++q) { s += v0[q]; s2 += v0[q]*v0[q]; s += v1[q]; s2 += v1[q]*v1[q]; }
    wred64(s, s2);
    float mu = s * (1.f / DIM);
    float rs = rsqrtf(s2 * (1.f / DIM) - mu * mu + EPSL);
    s8v ob;
    f4v o0, o1;
#pragma unroll
    for (int q = 0; q < 4; ++q) {
      float a = (v0[q] - mu) * rs * w0[q] + b0[q];
      a = a / (1.f + __expf(-a));
      unsigned short ua = f2b(a);
      ob[q] = (short)ua; o0[q] = b2f(ua);
      float e = (v1[q] - mu) * rs * w1[q] + b1[q];
      e = e / (1.f + __expf(-e));
      unsigned short ue = f2b(e);
      ob[4 + q] = (short)ue; o1[q] = b2f(ue);
    }
    *(s8v*)(y + ((size_t)b * LSEQ + (size_t)c * TCH + j) * DIM + c8) = ob;
    *(f4v*)&ls[j][c8]     = o0;
    *(f4v*)&ls[j][c8 + 4] = o1;
  }
}

// ---------------- fused: split-K(2) reduce + bias -> h(bf16) ; LN1+SiLU -> y(bf16) ; scan
__global__ void __launch_bounds__(512) red_ln_scan(
    const float* __restrict__ parts, unsigned short* __restrict__ h, const float* __restrict__ bias,
    const float* __restrict__ lnw, const float* __restrict__ lnb,
    const float* __restrict__ pr, const float* __restrict__ pi,
    unsigned short* __restrict__ y, float* __restrict__ stA)
{
  __shared__ float ls[TCH][DIM];
  const int d = threadIdx.x;
  const int c = blockIdx.x, b = blockIdx.y;
  const size_t rbase = ((size_t)b * LSEQ + (size_t)c * TCH) * DIM + d;
  const size_t st = (size_t)MR * DIM;
  const float bv = bias[d];
#pragma unroll 4
  for (int j = 0; j < TCH; ++j) {
    size_t o = rbase + (size_t)j * DIM;
    float v = parts[o] + parts[st + o] + bv;
    unsigned short hq = f2b(v);
    h[o] = hq;
    ls[j][d] = b2f(hq);   // use the rounded value everywhere downstream
  }
  __syncthreads();
  const int wave = threadIdx.x >> 6, lane = threadIdx.x & 63;
  ln_silu_emit(ls, y, lnw, lnb, wave, lane * 8, b, c);
  __syncthreads();
  float pre, pim; phz2p(pr[d], pi[d], pre, pim);
  float sre = 0.f, sim = 0.f;
#pragma unroll
  for (int j = 0; j < TCH; ++j) {
    float xv = ls[j][d];
    float nre = fmaf(pre, sre, fmaf(-pim, sim, xv));
    float nim = fmaf(pre, sim, pim * sre);
    sre = nre; sim = nim;
  }
  size_t o = (((size_t)b * NC + c) * DIM + d) * 2;
  stA[o] = sre; stA[o + 1] = sim;
}

// ---------------- fused: LN1+SiLU -> y(bf16) ; chunk-local scan -> stA (h bf16 read-only)
__global__ void __launch_bounds__(512) ln_scan(
    const unsigned short* __restrict__ h,
    const float* __restrict__ lnw, const float* __restrict__ lnb,
    const float* __restrict__ pr, const float* __restrict__ pi,
    unsigned short* __restrict__ y, float* __restrict__ stA)
{
  __shared__ float ls[TCH][DIM];
  const int d = threadIdx.x;
  const int c = blockIdx.x, b = blockIdx.y;
  const size_t rbase = ((size_t)b * LSEQ + (size_t)c * TCH) * DIM + d;
#pragma unroll 4
  for (int j = 0; j < TCH; ++j) ls[j][d] = b2f(h[rbase + (size_t)j * DIM]);
  __syncthreads();
  const int wave = threadIdx.x >> 6, lane = threadIdx.x & 63;
  ln_silu_emit(ls, y, lnw, lnb, wave, lane * 8, b, c);
  __syncthreads();
  float pre, pim; phz2p(pr[d], pi[d], pre, pim);
  float sre = 0.f, sim = 0.f;
#pragma unroll
  for (int j = 0; j < TCH; ++j) {
    float xv = ls[j][d];
    float nre = fmaf(pre, sre, fmaf(-pim, sim, xv));
    float nim = fmaf(pre, sim, pim * sre);
    sre = nre; sim = nim;
  }
  size_t o = (((size_t)b * NC + c) * DIM + d) * 2;
  stA[o] = sre; stA[o + 1] = sim;
}

// ---------------- scan_b: sequential carry over chunks (batch-8 load prefetch) [R7]
__global__ void __launch_bounds__(256) scan_b(
    const float* __restrict__ stA, float* __restrict__ carry,
    const float* __restrict__ pr, const float* __restrict__ pi,
    const float* __restrict__ lcr, const float* __restrict__ lci)
{
  int idx = blockIdx.x * 256 + threadIdx.x;   // 0..NB*DIM-1
  int b = idx >> 9, d = idx & (DIM - 1);
  float pre, pim; phz2p(pr[d], pi[d], pre, pim);
  float qre = pre, qim = pim;                  // p^TCH, TCH=16 -> 4 squarings
#pragma unroll
  for (int t = 0; t < 4; ++t) { float nr = qre*qre - qim*qim; float ni = 2.f*qre*qim; qre = nr; qim = ni; }
  float cre = lcr[d], cim = lci[d];
  const size_t base = (size_t)b * NC * DIM * 2 + (size_t)d * 2;
  for (int c0 = 0; c0 < NC; c0 += 8) {
    float ar[8], ai[8];
#pragma unroll
    for (int k = 0; k < 8; ++k) {
      size_t o = base + (size_t)(c0 + k) * DIM * 2;
      ar[k] = stA[o]; ai[k] = stA[o + 1];
    }
#pragma unroll
    for (int k = 0; k < 8; ++k) {
      size_t o = base + (size_t)(c0 + k) * DIM * 2;
      carry[o] = cre; carry[o + 1] = cim;
      float nr = fmaf(qre, cre, fmaf(-qim, cim, ar[k]));
      float ni = fmaf(qre, cim, fmaf(qim, cre, ai[k]));
      cre = nr; cim = ni;
    }
  }
}

// ---------------- fused: carry-replay (y bf16) + h(bf16) += Re(s)*scl ; LN2 -> yb (bf16)
__global__ void __launch_bounds__(512) scan_c_ln2(
    const unsigned short* __restrict__ y, unsigned short* __restrict__ h,
    const float* __restrict__ carry,
    const float* __restrict__ pr, const float* __restrict__ pi,
    const float* __restrict__ scl,
    const float* __restrict__ lnw, const float* __restrict__ lnb,
    unsigned short* __restrict__ yb)
{
  __shared__ float ls[TCH][DIM];
  const int d = threadIdx.x;
  const int c = blockIdx.x, b = blockIdx.y;
  float pre, pim; phz2p(pr[d], pi[d], pre, pim);
  size_t co = (((size_t)b * NC + c) * DIM + d) * 2;
  float sre = carry[co], sim = carry[co + 1];
  const float sc = scl[d];
  const size_t rbase = ((size_t)b * LSEQ + (size_t)c * TCH) * DIM + d;
#pragma unroll 4
  for (int j = 0; j < TCH; ++j) {
    size_t o = rbase + (size_t)j * DIM;
    float xv = b2f(y[o]);
    float nre = fmaf(pre, sre, fmaf(-pim, sim, xv));
    float nim = fmaf(pre, sim, pim * sre);
    sre = nre; sim = nim;
    float hv = b2f(h[o]) + sre * sc;
    unsigned short hq = f2b(hv);
    h[o] = hq;
    ls[j][d] = b2f(hq);
  }
  __syncthreads();
  const int wave = threadIdx.x >> 6, lane = threadIdx.x & 63;
  const int c8 = lane * 8;
  f4v w0 = *(const f4v*)(lnw + c8), w1 = *(const f4v*)(lnw + c8 + 4);
  f4v b0 = *(const f4v*)(lnb + c8), b1 = *(const f4v*)(lnb + c8 + 4);
#pragma unroll
  for (int jj = 0; jj < 2; ++jj) {
    int j = wave * 2 + jj;
    f4v v0 = *(const f4v*)&ls[j][c8];
    f4v v1 = *(const f4v*)&ls[j][c8 + 4];
    float s = 0.f, s2 = 0.f;
#pragma unroll
    for (int q = 0; q < 4; ++q) { s += v0[q]; s2 += v0[q]*v0[q]; s += v1[q]; s2 += v1[q]*v1[q]; }
    wred64(s, s2);
    float mu = s * (1.f / DIM);
    float rs = rsqrtf(s2 * (1.f / DIM) - mu * mu + EPSL);
    s8v o;
#pragma unroll
    for (int q = 0; q < 4; ++q) {
      o[q]     = (short)f2b((v0[q] - mu) * rs * w0[q] + b0[q]);
      o[4 + q] = (short)f2b((v1[q] - mu) * rs * w1[q] + b1[q]);
    }
    *(s8v*)(yb + ((size_t)b * LSEQ + (size_t)c * TCH + j) * DIM + c8) = o;
  }
}

// ---------------- fused: final LN -> yb (bf16); h bf16 read-only ----------------
__global__ void __launch_bounds__(512) ln_final(
    const unsigned short* __restrict__ h,
    const float* __restrict__ lnw, const float* __restrict__ lnb,
    unsigned short* __restrict__ yb)
{
  __shared__ float ls[TCH][DIM];
  const int d = threadIdx.x;
  const int c = blockIdx.x, b = blockIdx.y;
  const size_t rbase = ((size_t)b * LSEQ + (size_t)c * TCH) * DIM + d;
#pragma unroll 4
  for (int j = 0; j < TCH; ++j) ls[j][d] = b2f(h[rbase + (size_t)j * DIM]);
  __syncthreads();
  const int wave = threadIdx.x >> 6, lane = threadIdx.x & 63;
  const int c8 = lane * 8;
  f4v w0 = *(const f4v*)(lnw + c8), w1 = *(const f4v*)(lnw + c8 + 4);
  f4v b0 = *(const f4v*)(lnb + c8), b1 = *(const f4v*)(lnb + c8 + 4);
#pragma unroll
  for (int jj = 0; jj < 2; ++jj) {
    int j = wave * 2 + jj;
    f4v v0 = *(const f4v*)&ls[j][c8];
    f4v v1 = *(const f4v*)&ls[j][c8 + 4];
    float s = 0.f, s2 = 0.f;
#pragma unroll
    for (int q = 0; q < 4; ++q) { s += v0[q]; s2 += v0[q]*v0[q]; s += v1[q]; s2 += v1[q]*v1[q]; }
    wred64(s, s2);
    float mu = s * (1.f / DIM);
    float rs = rsqrtf(s2 * (1.f / DIM) - mu * mu + EPSL);
    s8v o;
#pragma unroll
    for (int q = 0; q < 4; ++q) {
      o[q]     = (short)f2b((v0[q] - mu) * rs * w0[q] + b0[q]);
      o[4 + q] = (short)f2b((v1[q] - mu) * rs * w1[q] + b1[q]);
    }
    *(s8v*)(yb + ((size_t)b * LSEQ + (size_t)c * TCH + j) * DIM + c8) = o;
  }
}

// ---------------- pipelined bf16 MFMA GEMM, A[M,K] x B[N,K]^T, 128xBN ----------------
// Depth-2 counted-vmcnt pipeline, 3 LDS buffer sets (R5-proven sync structure).
// BN in {64,128,256}; blocks/CU = 4/3/2. Template fully generic in BN.
// EPI 0: Cf = acc+bias ; EPI 1: Cb = bf16(silu(acc+bias)) ;
// EPI 2: Cb(bf16 h) RMW: h = bf16(b2f(h) + acc + bias) ;
// EPI 3: Cf[bz*MR*N + off] = acc (raw split-K partial, no bias)
template<int EPI, int BN>
__global__ void __launch_bounds__(256, BN == 64 ? 4 : (BN == 256 ? 2 : 3)) gemm_p(
    const unsigned short* __restrict__ A, const unsigned short* __restrict__ Bm,
    const float* __restrict__ bias,
    float* __restrict__ Cf, unsigned short* __restrict__ Cb,
    int N, int Keff, int lda, int ldb)
{
  constexpr int WN  = BN / 2;        // per-wave N extent
  constexpr int NJ  = WN / 16;       // N fragments per wave
  constexpr int VPT = 2 + BN / 64;   // vmem instrs per tile per thread
  __shared__ unsigned short As[3][128 * 32];
  __shared__ unsigned short Bs[3][BN * 32];
  const int tid  = threadIdx.x;
  const int lane = tid & 63, wave = tid >> 6;
  const int wm = wave >> 1, wn = wave & 1;
  const int fr = lane & 15, fq = lane >> 4;
  const int bz = blockIdx.z;

  // chunked bijective XCD swizzle (all grids have nwg_xy % 8 == 0)
  int bx, by;
  {
    int gx = gridDim.x;
    int nwg = gx * gridDim.y;
    int b = blockIdx.y * gx + blockIdx.x;
    int lid = (b & 7) * (nwg >> 3) + (b >> 3);
    bx = lid % gx; by = lid / gx;
  }
  const int m0 = by * 128, n0 = bx * BN;
  const int koff = bz * Keff;
  const int nkt = Keff >> 5;

  f4v acc[4][NJ];
#pragma unroll
  for (int i = 0; i < 4; ++i)
#pragma unroll
    for (int j = 0; j < NJ; ++j) acc[i][j] = (f4v){0.f, 0.f, 0.f, 0.f};

  const int row2 = tid >> 2, col2 = (tid & 3) << 3;
  auto stage = [&](int buf, int kt) {
    const unsigned short* Ab = A  + (size_t)m0 * lda + koff + kt * 32;
    const unsigned short* Bb = Bm + (size_t)n0 * ldb + koff + kt * 32;
    gld16(Ab + (size_t)row2 * lda + col2,        &As[buf][tid * 8]);
    gld16(Ab + (size_t)(row2 + 64) * lda + col2, &As[buf][(256 + tid) * 8]);
#pragma unroll
    for (int r = 0; r < BN / 64; ++r)
      gld16(Bb + (size_t)(row2 + 64 * r) * ldb + col2, &Bs[buf][(r * 256 + tid) * 8]);
  };

  stage(0, 0);
  stage(1, 1);

  int b0 = 0, b1 = 1, b2 = 2;
  for (int kt = 0; kt < nkt; ++kt) {
    bool pf = (kt + 2 < nkt);
    if (pf) stage(b2, kt + 2);
    if (pf)                    wvm<2 * VPT>();  // tiles kt+1,kt+2 in flight; kt retired
    else if (kt + 1 < nkt)     wvm<VPT>();
    else                       wvm<0>();
    __builtin_amdgcn_s_barrier();
    __builtin_amdgcn_sched_barrier(0);
    bf8v av[4], bv[NJ];
#pragma unroll
    for (int i = 0; i < 4; ++i)
      av[i] = *(const bf8v*)&As[b0][(wm * 64 + i * 16 + fr) * 32 + fq * 8];
#pragma unroll
    for (int j = 0; j < NJ; ++j)
      bv[j] = *(const bf8v*)&Bs[b0][(wn * WN + j * 16 + fr) * 32 + fq * 8];
#pragma unroll
    for (int i = 0; i < 4; ++i)
#pragma unroll
      for (int j = 0; j < NJ; ++j)
        acc[i][j] = __builtin_amdgcn_mfma_f32_16x16x32_bf16(av[i], bv[j], acc[i][j], 0, 0, 0);
    __builtin_amdgcn_sched_barrier(0);
    __builtin_amdgcn_s_barrier();
    int t = b0; b0 = b1; b1 = b2; b2 = t;
  }

  // epilogue: C[m0 + wm*64 + i*16 + fq*4 + r][n0 + wn*WN + j*16 + fr]
  const size_t pbase = (EPI == 3) ? (size_t)bz * MR * N : 0;
#pragma unroll
  for (int j = 0; j < NJ; ++j) {
    const int col = n0 + wn * WN + j * 16 + fr;
    const float bsv = (EPI == 3) ? 0.f : bias[col];
#pragma unroll
    for (int i = 0; i < 4; ++i) {
#pragma unroll
      for (int r = 0; r < 4; ++r) {
        const int row = m0 + wm * 64 + i * 16 + fq * 4 + r;
        const size_t off = (size_t)row * N + col;
        float v = acc[i][j][r] + bsv;
        if constexpr (EPI == 0) {
          Cf[off] = v;
        } else if constexpr (EPI == 1) {
          float sv = v / (1.f + __expf(-v));
          Cb[off] = f2b(sv);
        } else if constexpr (EPI == 2) {
          Cb[off] = f2b(b2f(Cb[off]) + v);   // bf16 residual RMW
        } else {
          Cf[pbase + off] = v;
        }
      }
    }
  }
}

// ---------------- orchestration ----------------
extern "C" void kernel_launch(void* const* d_in, const int* in_sizes, int n_in,
                              void* d_out, int out_size, void* d_ws, size_t ws_size,
                              hipStream_t stream)
{
  (void)in_sizes; (void)n_in; (void)out_size; (void)ws_size;
  const float* x    = (const float*)d_in[0];
  const float* Win  = (const float*)d_in[1];
  const float* bin  = (const float*)d_in[2];
  const float* ln1w = (const float*)d_in[3];
  const float* ln1b = (const float*)d_in[4];
  const float* phzr = (const float*)d_in[5];
  const float* phzi = (const float*)d_in[6];
  const float* lcr  = (const float*)d_in[7];
  const float* lci  = (const float*)d_in[8];
  const float* scl  = (const float*)d_in[9];
  const float* ln2w = (const float*)d_in[10];
  const float* ln2b = (const float*)d_in[11];
  const float* W1   = (const float*)d_in[12];
  const float* b1   = (const float*)d_in[13];
  const float* W2   = (const float*)d_in[14];
  const float* b2   = (const float*)d_in[15];
  const float* lnlw = (const float*)d_in[16];
  const float* lnlb = (const float*)d_in[17];
  const float* Wout = (const float*)d_in[18];
  const float* bout = (const float*)d_in[19];

  char* wsp = (char*)d_ws;
  auto alloc = [&](size_t bytes) { char* p = wsp; wsp += (bytes + 255) & ~(size_t)255; return p; };
  unsigned short* h     = (unsigned short*)alloc((size_t)MR * DIM * 2);   // bf16 residual
  unsigned short* y     = (unsigned short*)alloc((size_t)MR * DIM * 2);   // bf16
  unsigned short* yb    = (unsigned short*)alloc((size_t)MR * DIM * 2);
  unsigned short* Winb  = (unsigned short*)alloc((size_t)DIM * VOCAB * 2);
  unsigned short* W1b   = (unsigned short*)alloc((size_t)DEPTH * DFF * DIM * 2);
  unsigned short* W2b   = (unsigned short*)alloc((size_t)DEPTH * DIM * DFF * 2);
  unsigned short* Woutb = (unsigned short*)alloc((size_t)VOCAB * DIM * 2);
  float*          stA   = (float*)alloc((size_t)NB * NC * DIM * 2 * 4);
  float*          carry = (float*)alloc((size_t)NB * NC * DIM * 2 * 4);

  // d_out (128 MiB) doubles as scratch:
  //   xb    (bf16, 64 MiB) at [0, 64Mi)        — dies after token_in GEMM
  //   parts (2 x 16.8 MB f32) at [64Mi, ~98Mi) — token split-K partials (disjoint from xb)
  //   act1  (bf16, 32 MiB) at [0, 32Mi)        — per-layer FFN activation (after xb dead)
  // Final GEMM overwrites d_out fully.
  unsigned short* xb    = (unsigned short*)d_out;
  unsigned short* act1  = (unsigned short*)d_out;
  float*          parts = (float*)((char*)d_out + ((size_t)64 << 20));

  dim3 blk(256);
  dim3 fblk(512);
  dim3 fgrid(NC, NB);
  // one merged convert dispatch: x + Win + W1 + W2 + Wout
  cvt_all<<<dim3((NX8 + NW8 + N18 + N28 + NO8) / 256), blk, 0, stream>>>(
      x, Win, W1, W2, Wout, xb, Winb, W1b, W2b, Woutb);

  // h = xb @ Win^T + bin : BN=128, split-K=2 (Keff=2048) -> 4x64x2 = 512 blocks
  gemm_p<3, 128><<<dim3(DIM / 128, MR / 128, 2), blk, 0, stream>>>(
      xb, Winb, nullptr, parts, nullptr, DIM, VOCAB / 2, VOCAB, VOCAB);
  // h = bf16(reduce2(parts)+bin) ; y = silu(LN1_0(h)) (bf16) ; stA   (fused)
  red_ln_scan<<<fgrid, fblk, 0, stream>>>(parts, h, bin, ln1w, ln1b, phzr, phzi, y, stA);

  for (int l = 0; l < DEPTH; ++l) {
    scan_b<<<dim3((NB * DIM) / 256), blk, 0, stream>>>(stA, carry, phzr + l * DIM, phzi + l * DIM,
                                                       lcr + l * DIM, lci + l * DIM);
    scan_c_ln2<<<fgrid, fblk, 0, stream>>>(y, h, carry, phzr + l * DIM, phzi + l * DIM,
                                           scl + l * DIM, ln2w + l * DIM, ln2b + l * DIM, yb);
    // act1 = silu(yb @ W1^T + b1), bf16 (BN=256: grid 8x64 = 512 blocks)
    gemm_p<1, 256><<<dim3(DFF / 256, MR / 128, 1), blk, 0, stream>>>(
        yb, W1b + (size_t)l * DFF * DIM, b1 + l * DFF, nullptr, act1, DFF, DIM, DIM, DIM);
    // h += act1 @ W2^T + b2  (BN=64, bf16 residual RMW in epilogue)
    gemm_p<2, 64><<<dim3(DIM / 64, MR / 128, 1), blk, 0, stream>>>(
        act1, W2b + (size_t)l * DIM * DFF, b2 + l * DIM, nullptr, h, DIM, DFF, DFF, DFF);
    if (l < DEPTH - 1) {
      ln_scan<<<fgrid, fblk, 0, stream>>>(h, ln1w + (l + 1) * DIM, ln1b + (l + 1) * DIM,
                                          phzr + (l + 1) * DIM, phzi + (l + 1) * DIM, y, stA);
    }
  }
  // final: yb = LN_last(h)
  ln_final<<<fgrid, fblk, 0, stream>>>(h, lnlw, lnlb, yb);
  // out = yb @ Wout^T + bout (BN=256: grid 16x64 = 1024 blocks)
  gemm_p<0, 256><<<dim3(VOCAB / 256, MR / 128, 1), blk, 0, stream>>>(
      yb, Woutb, bout, (float*)d_out, nullptr, VOCAB, DIM, DIM, DIM);
}